// Round 5
// baseline (899.387 us; speedup 1.0000x reference)
//
#include <hip/hip_runtime.h>

#define NTOK 8192
#define DMODEL 512
#define NWORDS 128  // NTOK/64 mask words per row
#define ESTRIDE (2 * NTOK)  // Eh row stride in halfs: row r lives in attn row r's region

typedef _Float16 f16;
typedef _Float16 f16x4 __attribute__((ext_vector_type(4)));
typedef _Float16 f16x8 __attribute__((ext_vector_type(8)));
typedef float f32x4 __attribute__((ext_vector_type(4)));
typedef unsigned long long u64;

// async global->LDS, 16B per lane; lds dest = wave-uniform base + lane*16
__device__ __forceinline__ void async_ld16(const void* g, void* l) {
  __builtin_amdgcn_global_load_lds((const __attribute__((address_space(1))) void*)g,
                                   (__attribute__((address_space(3))) void*)l, 16, 0, 0);
}

// ---------------- pack fp32 -> f16 (elementwise, float4 vectorized) ----------------
__global__ void pack_f16(const float* __restrict__ s, f16* __restrict__ d, int n) {
  int i = (blockIdx.x * 256 + threadIdx.x) * 4;
  if (i >= n) return;
  float4 v = *(const float4*)(s + i);
  f16x4 h; h.x = (f16)v.x; h.y = (f16)v.y; h.z = (f16)v.z; h.w = (f16)v.w;
  *(f16x4*)(d + i) = h;
}

// ------------- mask int32 -> bitmask: 256MB -> 8MB, pure streaming -------------
__global__ __launch_bounds__(256) void pack_mask(const int* __restrict__ mask,
                                                 u64* __restrict__ bits) {
  int wave = (blockIdx.x * 256 + threadIdx.x) >> 6;
  int lane = threadIdx.x & 63;
  size_t W0 = (size_t)wave * 8;
#pragma unroll
  for (int i = 0; i < 8; ++i) {
    int m = __builtin_nontemporal_load(mask + (W0 + i) * 64 + lane);  // read-once
    u64 b = __ballot(m != 0);  // bit l = col W*64+l
    if (lane == 0) bits[W0 + i] = b;
  }
}

// ---------------- transpose V [NTOK][D] -> Vt [D][NTOK] ----------------
__global__ __launch_bounds__(256) void transpose_f16(const f16* __restrict__ src,
                                                     f16* __restrict__ dst) {
  __shared__ f16 T[64][72];  // +8 pad breaks bank alignment
  int t = threadIdx.x;
  int tok0 = blockIdx.x * 64, d0 = blockIdx.y * 64;
#pragma unroll
  for (int i = 0; i < 2; ++i) {
    int row = (t >> 3) + i * 32;
    int col = (t & 7) * 8;
    f16x8 v = *(const f16x8*)(src + (size_t)(tok0 + row) * DMODEL + d0 + col);
    *(f16x8*)(&T[row][col]) = v;
  }
  __syncthreads();
#pragma unroll
  for (int i = 0; i < 2; ++i) {
    int od = (t >> 3) + i * 32;
    int ot = (t & 7) * 8;
    f16x8 v;
#pragma unroll
    for (int j = 0; j < 8; ++j) v[j] = T[ot + j][od];
    *(f16x8*)(dst + (size_t)(d0 + od) * NTOK + tok0 + ot) = v;
  }
}

// ---- stage 128x64 f16 tile, XOR-swizzled (rule #21: linear LDS dest via
// global_load_lds + pre-swizzled GLOBAL column; reader applies the same XOR).
// LDS[row][u] = G[row][u ^ ((row&7)*8)]  (XOR on half-index bits 3..5).
__device__ __forceinline__ void stage128x64(const f16* G, int r0, int k0, int rs,
                                            f16* lds, int t) {
  int wv = t >> 6;
  int sw = (((t & 7) ^ ((t >> 3) & 7)) * 8);  // row&7 == (t>>3)&7 for all 4 iters
  const f16* g = G + (size_t)(r0 + (t >> 3)) * rs + k0 + sw;
#pragma unroll
  for (int i = 0; i < 4; ++i)
    async_ld16(g + (size_t)i * 32 * rs, (char*)lds + i * 4096 + wv * 1024);
}

// shared 128x128 C = A * B^T K-loop, BK=64, DOUBLE-BUFFERED prefetch:
// per iter {stage next into other buf; compute cur; sync(drain)} - one barrier/step,
// stage latency hidden under ds_read+MFMA. As/Bs are 2x(128*64) each.
template <int RS>
__device__ __forceinline__ void gemm128(const f16* A, const f16* B, int m0, int n0,
                                        f16* As, f16* Bs, int t, f32x4 (&acc)[4][4]) {
  int lane = t & 63, quad = lane >> 4, l15 = lane & 15, wv = t >> 6;
  int m_off = (wv & 1) * 64, n_off = (wv >> 1) * 64;
  stage128x64(A, m0, 0, RS, As, t);
  stage128x64(B, n0, 0, RS, Bs, t);
  __syncthreads();
  for (int kt = 0; kt < RS; kt += 64) {
    int cur = (kt >> 6) & 1;
    if (kt + 64 < RS) {  // prefetch next K-tile into the other buffer
      stage128x64(A, m0, kt + 64, RS, As + (cur ^ 1) * 8192, t);
      stage128x64(B, n0, kt + 64, RS, Bs + (cur ^ 1) * 8192, t);
    }
    const f16* Ac = As + cur * 8192;
    const f16* Bc = Bs + cur * 8192;
#pragma unroll
    for (int ks = 0; ks < 2; ++ks) {
      // de-swizzle: want G[row][ks*32+quad*8]; row&7 == l15&7
      int sl = (((ks << 2) | quad) ^ (l15 & 7)) * 8;
      f16x8 af[4], bf[4];
#pragma unroll
      for (int mt = 0; mt < 4; ++mt)
        af[mt] = *(const f16x8*)(Ac + (m_off + mt * 16 + l15) * 64 + sl);
#pragma unroll
      for (int nt = 0; nt < 4; ++nt)
        bf[nt] = *(const f16x8*)(Bc + (n_off + nt * 16 + l15) * 64 + sl);
#pragma unroll
      for (int mt = 0; mt < 4; ++mt)
#pragma unroll
        for (int nt = 0; nt < 4; ++nt)
          acc[mt][nt] = __builtin_amdgcn_mfma_f32_16x16x32_f16(af[mt], bf[nt], acc[mt][nt], 0, 0, 0);
    }
    __syncthreads();  // drains prefetch vmcnt AFTER compute; protects cur for overwrite
  }
}

// ---------------- QKV: C[i,j] = sum_k X[i,k] * W[j,k] ----------------
__global__ __launch_bounds__(256) void qkv_gemm(const f16* __restrict__ X,
                                                const f16* __restrict__ Wall,
                                                f16* __restrict__ Out) {
  __shared__ f16 As[2 * 128 * 64];
  __shared__ f16 Bs[2 * 128 * 64];
  int t = threadIdx.x;
  int z = blockIdx.z;
  const f16* B = Wall + (size_t)z * DMODEL * DMODEL;
  f16* C = Out + (size_t)z * NTOK * DMODEL;
  int m0 = blockIdx.y * 128, n0 = blockIdx.x * 128;
  int lane = t & 63, wv = t >> 6, quad = lane >> 4, l15 = lane & 15;
  int m_off = (wv & 1) * 64, n_off = (wv >> 1) * 64;
  f32x4 acc[4][4] = {};
  gemm128<DMODEL>(X, B, m0, n0, As, Bs, t, acc);
#pragma unroll
  for (int mt = 0; mt < 4; ++mt)
#pragma unroll
    for (int nt = 0; nt < 4; ++nt)
#pragma unroll
      for (int r = 0; r < 4; ++r) {
        int row = m0 + m_off + mt * 16 + quad * 4 + r;
        int col = n0 + n_off + nt * 16 + l15;
        C[(size_t)row * DMODEL + col] = (f16)acc[mt][nt][r];
      }
}

// ---- scores: Eh(f16) = exp(masked QK^T/sqrt(D)); rowsum atomics; coalesced nt-store ----
// Eh row r is stored at half-offset r*ESTRIDE (the first half of attn row r's fp32
// region) so the later in-place fp32 expansion only aliases its OWN row.
__global__ __launch_bounds__(256) void scores2(const f16* __restrict__ Q,
                                               const f16* __restrict__ Kh,
                                               const u64* __restrict__ bits,
                                               f16* __restrict__ Eh,
                                               float* __restrict__ rowsum) {
  __shared__ f16 SM[2 * 128 * 128];  // 64KB: As dbuf | Bs dbuf; E tile reuses [0,16384)
  f16* As = SM;
  f16* Bs = SM + 16384;
  int t = threadIdx.x;
  // T1 XCD swizzle: each XCD owns 8 m-panels; within chunk m varies fastest so
  // each K n-panel is reused 8x back-to-back; Q panels (1MB/XCD) stay L2-resident.
  int orig = blockIdx.x + (blockIdx.y << 6);  // 4096 blocks, %8==0 -> bijective
  int wg = (orig & 7) * 512 + (orig >> 3);
  int m0 = (((wg >> 9) * 8 + (wg & 7))) * 128;
  int n0 = ((wg >> 3) & 63) * 128;
  int lane = t & 63, wv = t >> 6, quad = lane >> 4, l15 = lane & 15;
  int m_off = (wv & 1) * 64, n_off = (wv >> 1) * 64;
  f32x4 acc[4][4] = {};
  gemm128<DMODEL>(Q, Kh, m0, n0, As, Bs, t, acc);
  const float scale = 0.044194173824159216f;  // 1/sqrt(512)
  // gemm128's final barrier synchronized all waves; SM is free for the E tile.
#pragma unroll
  for (int mt = 0; mt < 4; ++mt)
#pragma unroll
    for (int r = 0; r < 4; ++r) {
      int lrow = m_off + mt * 16 + quad * 4 + r;
      int row = m0 + lrow;
      u64 w = bits[(size_t)row * NWORDS + ((n0 + n_off) >> 6)];  // 64 cols of this wave
      float rs = 0.f;
#pragma unroll
      for (int nt = 0; nt < 4; ++nt) {
        float s = acc[mt][nt][r] * scale;
        float e = ((w >> (nt * 16 + l15)) & 1) ? 0.f : __expf(s);
        rs += e;
        int col = n_off + nt * 16 + l15;
        // XOR-swizzle 8-half blocks with row bits -> conflict-lean, bijective per row
        int phys = (((col >> 3) ^ (lrow & 15)) << 3) | (col & 7);
        SM[lrow * 128 + phys] = (f16)e;
      }
      rs += __shfl_xor(rs, 1);
      rs += __shfl_xor(rs, 2);
      rs += __shfl_xor(rs, 4);
      rs += __shfl_xor(rs, 8);
      if (l15 == 0) atomicAdd(&rowsum[row], rs);
    }
  __syncthreads();
#pragma unroll
  for (int p = 0; p < 8; ++p) {  // coalesced f16x8 nt-stores: 1KB per wave-instr
    int lrow = p * 16 + (t >> 4);
    int cb = t & 15;
    f16x8 v = *(const f16x8*)(SM + lrow * 128 + ((cb ^ (lrow & 15)) << 3));
    __builtin_nontemporal_store(v, (f16x8*)(Eh + (size_t)(m0 + lrow) * ESTRIDE + n0 + cb * 8));
  }
}

// ---- pv staging: BK=32 tiles, XOR-swizzle on 16B slots (slot ^= row&3).
// Writer: linear LDS dest, pre-swizzled global column. 512 threads.
__device__ __forceinline__ void stage_pv(const f16* __restrict__ Eh,
                                         const f16* __restrict__ Vt, int r0, int kt,
                                         f16* Es, f16* Vs, int t) {
  int wv = t >> 6;
  int srcsw = (((t & 3) ^ ((t >> 2) & 3)) * 8);
  async_ld16(Eh + (size_t)(r0 + (t >> 2)) * ESTRIDE + kt + srcsw, (char*)Es + wv * 1024);
#pragma unroll
  for (int i = 0; i < 4; ++i)
    async_ld16(Vt + (size_t)(i * 128 + (t >> 2)) * NTOK + kt + srcsw,
               (char*)Vs + i * 8192 + wv * 1024);
}

// ------- cntx = (Eh @ V) * rinv; BK=32 double-buffered prefetch; K-chunked atomics -------
__global__ __launch_bounds__(512, 2) void pv_kernel(const f16* __restrict__ Eh,
                                                    const float* __restrict__ rowsum,
                                                    const f16* __restrict__ Vt,
                                                    float* __restrict__ cntx) {
  __shared__ f16 Es[2][128 * 32];  // 16 KB
  __shared__ f16 Vs[2][512 * 32];  // 64 KB
  int t = threadIdx.x;
  // XCD swizzle: 256 blocks; each XCD-chunk of 32 shares one Vt k-chunk (2MB, L2-fit)
  int orig = blockIdx.x + (blockIdx.y << 6);
  int wg = (orig & 7) * 32 + (orig >> 3);
  int r0 = (wg & 63) * 128;
  int k0 = (wg >> 6) * 2048;
  int lane = t & 63, wv = t >> 6, quad = lane >> 4, l15 = lane & 15;
  int m_off = (wv & 1) * 64, n_off = (wv >> 1) * 128;
  int sl2 = (quad ^ (l15 & 3)) * 8;  // de-swizzle for reads
  f32x4 acc[4][8] = {};
  stage_pv(Eh, Vt, r0, k0, Es[0], Vs[0], t);
  __syncthreads();
  for (int i = 0; i < 64; ++i) {
    int cur = i & 1;
    if (i < 63) stage_pv(Eh, Vt, r0, k0 + (i + 1) * 32, Es[cur ^ 1], Vs[cur ^ 1], t);
    const f16* Ec = Es[cur];
    const f16* Vc = Vs[cur];
    f16x8 af[4], bf[8];
#pragma unroll
    for (int mt = 0; mt < 4; ++mt)
      af[mt] = *(const f16x8*)(Ec + (m_off + mt * 16 + l15) * 32 + sl2);
#pragma unroll
    for (int nt = 0; nt < 8; ++nt)
      bf[nt] = *(const f16x8*)(Vc + (n_off + nt * 16 + l15) * 32 + sl2);
#pragma unroll
    for (int mt = 0; mt < 4; ++mt)
#pragma unroll
      for (int nt = 0; nt < 8; ++nt)
        acc[mt][nt] = __builtin_amdgcn_mfma_f32_16x16x32_f16(af[mt], bf[nt], acc[mt][nt], 0, 0, 0);
    __syncthreads();  // drains prefetch AFTER compute; protects cur for overwrite
  }
#pragma unroll
  for (int mt = 0; mt < 4; ++mt)
#pragma unroll
    for (int r = 0; r < 4; ++r) {
      int row = r0 + m_off + mt * 16 + quad * 4 + r;
      float ri = 1.0f / rowsum[row];
#pragma unroll
      for (int nt = 0; nt < 8; ++nt) {
        int col = n_off + nt * 16 + l15;
        atomicAdd(&cntx[(size_t)row * DMODEL + col], acc[mt][nt][r] * ri);
      }
    }
}

// ---- in-place f16 E -> fp32 attn * rinv, pure-register (no LDS, no barriers).
// One wave per row. All 16 loads precede all stores in program order; src/dst
// may alias so the compiler cannot hoist a store above a load; the HW waits
// (wave-level vmcnt) cover all 64 lanes' loads before the first dependent store.
// fp32 write of col c only clobbers f16 cols >= c, all within this wave's row.
__global__ __launch_bounds__(256) void expand_attn(float* __restrict__ attn,
                                                   const float* __restrict__ rowsum) {
  int t = threadIdx.x;
  int wv = t >> 6, lane = t & 63;
  int row = blockIdx.x * 4 + wv;
  float ri = 1.0f / rowsum[row];
  const f16* src = (const f16*)(attn + (size_t)row * NTOK);
  float* dst = attn + (size_t)row * NTOK;
  f16x8 v0, v1, v2, v3, v4, v5, v6, v7, v8, v9, va, vb, vc, vd, ve, vf;
#define LD(i, reg) reg = __builtin_nontemporal_load((const f16x8*)(src + (i) * 512 + lane * 8))
  LD(0, v0); LD(1, v1); LD(2, v2); LD(3, v3); LD(4, v4); LD(5, v5); LD(6, v6); LD(7, v7);
  LD(8, v8); LD(9, v9); LD(10, va); LD(11, vb); LD(12, vc); LD(13, vd); LD(14, ve); LD(15, vf);
#undef LD
  asm volatile("" ::: "memory");  // compiler barrier: pin all loads before any store
#define ST(i, reg)                                                            \
  {                                                                           \
    f32x4 lo, hi;                                                             \
    lo.x = (float)reg[0] * ri; lo.y = (float)reg[1] * ri;                     \
    lo.z = (float)reg[2] * ri; lo.w = (float)reg[3] * ri;                     \
    hi.x = (float)reg[4] * ri; hi.y = (float)reg[5] * ri;                     \
    hi.z = (float)reg[6] * ri; hi.w = (float)reg[7] * ri;                     \
    __builtin_nontemporal_store(lo, (f32x4*)(dst + (i) * 512 + lane * 8));    \
    __builtin_nontemporal_store(hi, (f32x4*)(dst + (i) * 512 + lane * 8 + 4)); \
  }
  ST(0, v0); ST(1, v1); ST(2, v2); ST(3, v3); ST(4, v4); ST(5, v5); ST(6, v6); ST(7, v7);
  ST(8, v8); ST(9, v9); ST(10, va); ST(11, vb); ST(12, vc); ST(13, vd); ST(14, ve); ST(15, vf);
#undef ST
}

extern "C" void kernel_launch(void* const* d_in, const int* in_sizes, int n_in,
                              void* d_out, int out_size, void* d_ws, size_t ws_size,
                              hipStream_t stream) {
  const float* x  = (const float*)d_in[0];
  const int* mask = (const int*)d_in[1];
  const float* Wq = (const float*)d_in[2];
  const float* Wk = (const float*)d_in[3];
  const float* Wv = (const float*)d_in[4];
  float* cntx = (float*)d_out;
  float* attn = (float*)d_out + (size_t)NTOK * DMODEL;

  // workspace (f16): xh 8MB | Wh 1.5MB | Q,K,V 24MB | Vt 8MB | rowsum 32KB  (~42MB)
  f16* xh = (f16*)d_ws;
  f16* Wh = xh + (size_t)NTOK * DMODEL;
  f16* QKV = Wh + (size_t)3 * DMODEL * DMODEL;
  f16* Qh = QKV;
  f16* Kh = QKV + (size_t)NTOK * DMODEL;
  f16* Vh = QKV + (size_t)2 * NTOK * DMODEL;
  f16* Vt = QKV + (size_t)3 * NTOK * DMODEL;
  float* rowsum = (float*)(Vt + (size_t)NTOK * DMODEL);

  // bitmask (8MB) lives in the cntx output region: dead until after scores2.
  u64* bits = (u64*)cntx;
  // f16 E lives interleaved in the attn output region (first half of each fp32 row).
  f16* Eh = (f16*)attn;

  hipMemsetAsync(rowsum, 0, NTOK * sizeof(float), stream);

  pack_f16<<<dim3(NTOK * DMODEL / 1024), 256, 0, stream>>>(x, xh, NTOK * DMODEL);
  pack_f16<<<dim3(DMODEL * DMODEL / 1024), 256, 0, stream>>>(Wq, Wh, DMODEL * DMODEL);
  pack_f16<<<dim3(DMODEL * DMODEL / 1024), 256, 0, stream>>>(Wk, Wh + DMODEL * DMODEL, DMODEL * DMODEL);
  pack_f16<<<dim3(DMODEL * DMODEL / 1024), 256, 0, stream>>>(Wv, Wh + 2 * DMODEL * DMODEL, DMODEL * DMODEL);
  pack_mask<<<dim3(NTOK * NWORDS / 8 / 4), 256, 0, stream>>>(mask, bits);

  qkv_gemm<<<dim3(DMODEL / 128, NTOK / 128, 3), 256, 0, stream>>>(xh, Wh, QKV);
  transpose_f16<<<dim3(NTOK / 64, DMODEL / 64), 256, 0, stream>>>(Vh, Vt);
  scores2<<<dim3(NTOK / 128, NTOK / 128), 256, 0, stream>>>(Qh, Kh, bits, Eh, rowsum);

  // bits now dead; zero cntx for pv atomics
  hipMemsetAsync(cntx, 0, (size_t)NTOK * DMODEL * sizeof(float), stream);
  pv_kernel<<<dim3(NTOK / 128, 4), 512, 0, stream>>>(Eh, rowsum, Vt, cntx);
  expand_attn<<<dim3(NTOK / 4), 256, 0, stream>>>(attn, rowsum);
}

// Round 6
// 871.260 us; speedup vs baseline: 1.0323x; 1.0323x over previous
//
#include <hip/hip_runtime.h>

#define NTOK 8192
#define DMODEL 512
#define NWORDS 128  // NTOK/64 mask words per row
#define ESTRIDE (2 * NTOK)  // Eh row stride in halfs: row r lives in attn row r's region

typedef _Float16 f16;
typedef _Float16 f16x4 __attribute__((ext_vector_type(4)));
typedef _Float16 f16x8 __attribute__((ext_vector_type(8)));
typedef float f32x4 __attribute__((ext_vector_type(4)));
typedef unsigned long long u64;

// async global->LDS, 16B per lane; lds dest = wave-uniform base + lane*16
__device__ __forceinline__ void async_ld16(const void* g, void* l) {
  __builtin_amdgcn_global_load_lds((const __attribute__((address_space(1))) void*)g,
                                   (__attribute__((address_space(3))) void*)l, 16, 0, 0);
}

// ---------------- pack fp32 -> f16 (elementwise, float4 vectorized) ----------------
__global__ void pack_f16(const float* __restrict__ s, f16* __restrict__ d, int n) {
  int i = (blockIdx.x * 256 + threadIdx.x) * 4;
  if (i >= n) return;
  float4 v = *(const float4*)(s + i);
  f16x4 h; h.x = (f16)v.x; h.y = (f16)v.y; h.z = (f16)v.z; h.w = (f16)v.w;
  *(f16x4*)(d + i) = h;
}

// ------------- mask int32 -> bitmask: 256MB -> 8MB, pure streaming -------------
__global__ __launch_bounds__(256) void pack_mask(const int* __restrict__ mask,
                                                 u64* __restrict__ bits) {
  int wave = (blockIdx.x * 256 + threadIdx.x) >> 6;
  int lane = threadIdx.x & 63;
  size_t W0 = (size_t)wave * 8;
#pragma unroll
  for (int i = 0; i < 8; ++i) {
    int m = __builtin_nontemporal_load(mask + (W0 + i) * 64 + lane);  // read-once
    u64 b = __ballot(m != 0);  // bit l = col W*64+l
    if (lane == 0) bits[W0 + i] = b;
  }
}

// ---------------- transpose V [NTOK][D] -> Vt [D][NTOK] ----------------
__global__ __launch_bounds__(256) void transpose_f16(const f16* __restrict__ src,
                                                     f16* __restrict__ dst) {
  __shared__ f16 T[64][72];  // +8 pad breaks bank alignment
  int t = threadIdx.x;
  int tok0 = blockIdx.x * 64, d0 = blockIdx.y * 64;
#pragma unroll
  for (int i = 0; i < 2; ++i) {
    int row = (t >> 3) + i * 32;
    int col = (t & 7) * 8;
    f16x8 v = *(const f16x8*)(src + (size_t)(tok0 + row) * DMODEL + d0 + col);
    *(f16x8*)(&T[row][col]) = v;
  }
  __syncthreads();
#pragma unroll
  for (int i = 0; i < 2; ++i) {
    int od = (t >> 3) + i * 32;
    int ot = (t & 7) * 8;
    f16x8 v;
#pragma unroll
    for (int j = 0; j < 8; ++j) v[j] = T[ot + j][od];
    *(f16x8*)(dst + (size_t)(d0 + od) * NTOK + tok0 + ot) = v;
  }
}

// ---- stage 128x32 f16 tile, XOR-swizzled 16B slots (rule #21: linear LDS dest
// via global_load_lds + pre-swizzled GLOBAL slot; reader applies the same XOR).
// LDS[row][slot] = G[row][slot ^ (row&3)] (slots of 8 halfs). 2 issues/thread.
__device__ __forceinline__ void stage128x32(const f16* G, int r0, int k0, int rs,
                                            f16* lds, int t) {
  int wv = t >> 6;
  int srcsw = (((t & 3) ^ ((t >> 2) & 3)) * 8);
  const f16* g = G + (size_t)(r0 + (t >> 2)) * rs + k0 + srcsw;
  async_ld16(g, (char*)lds + wv * 1024);                         // rows 0..63
  async_ld16(g + (size_t)64 * rs, (char*)lds + 4096 + wv * 1024);  // rows 64..127
}

// shared 128x128 C = A * B^T K-loop, BK=32, DOUBLE-BUFFERED at the SAME 32KB
// footprint as single-buffered BK=64 (m132 lesson: never pay occupancy for dbuf).
// Per iter: {prefetch next tile -> other buf; ds_read+16 MFMA on cur; barrier}.
template <int RS>
__device__ __forceinline__ void gemm128(const f16* A, const f16* B, int m0, int n0,
                                        f16* As, f16* Bs, int t, f32x4 (&acc)[4][4]) {
  int lane = t & 63, quad = lane >> 4, l15 = lane & 15, wv = t >> 6;
  int m_off = (wv & 1) * 64, n_off = (wv >> 1) * 64;
  int sl = (quad ^ (l15 & 3)) * 8;  // de-swizzle: source slot quad at LDS slot quad^(row&3)
  stage128x32(A, m0, 0, RS, As, t);
  stage128x32(B, n0, 0, RS, Bs, t);
  __syncthreads();
  for (int kt = 0; kt < RS; kt += 32) {
    int cur = (kt >> 5) & 1;
    if (kt + 32 < RS) {  // prefetch next K-tile into the other buffer
      stage128x32(A, m0, kt + 32, RS, As + (cur ^ 1) * 4096, t);
      stage128x32(B, n0, kt + 32, RS, Bs + (cur ^ 1) * 4096, t);
    }
    const f16* Ac = As + cur * 4096;
    const f16* Bc = Bs + cur * 4096;
    f16x8 af[4], bf[4];
#pragma unroll
    for (int mt = 0; mt < 4; ++mt)
      af[mt] = *(const f16x8*)(Ac + (m_off + mt * 16 + l15) * 32 + sl);
#pragma unroll
    for (int nt = 0; nt < 4; ++nt)
      bf[nt] = *(const f16x8*)(Bc + (n_off + nt * 16 + l15) * 32 + sl);
#pragma unroll
    for (int mt = 0; mt < 4; ++mt)
#pragma unroll
      for (int nt = 0; nt < 4; ++nt)
        acc[mt][nt] = __builtin_amdgcn_mfma_f32_16x16x32_f16(af[mt], bf[nt], acc[mt][nt], 0, 0, 0);
    __syncthreads();  // drains prefetch vmcnt AFTER compute; protects cur for overwrite
  }
}

// ---------------- QKV: C[i,j] = sum_k X[i,k] * W[j,k] ----------------
__global__ __launch_bounds__(256) void qkv_gemm(const f16* __restrict__ X,
                                                const f16* __restrict__ Wall,
                                                f16* __restrict__ Out) {
  __shared__ f16 As[2 * 128 * 32];  // 16 KB
  __shared__ f16 Bs[2 * 128 * 32];  // 16 KB
  int t = threadIdx.x;
  int z = blockIdx.z;
  const f16* B = Wall + (size_t)z * DMODEL * DMODEL;
  f16* C = Out + (size_t)z * NTOK * DMODEL;
  int m0 = blockIdx.y * 128, n0 = blockIdx.x * 128;
  int lane = t & 63, wv = t >> 6, quad = lane >> 4, l15 = lane & 15;
  int m_off = (wv & 1) * 64, n_off = (wv >> 1) * 64;
  f32x4 acc[4][4] = {};
  gemm128<DMODEL>(X, B, m0, n0, As, Bs, t, acc);
#pragma unroll
  for (int mt = 0; mt < 4; ++mt)
#pragma unroll
    for (int nt = 0; nt < 4; ++nt)
#pragma unroll
      for (int r = 0; r < 4; ++r) {
        int row = m0 + m_off + mt * 16 + quad * 4 + r;
        int col = n0 + n_off + nt * 16 + l15;
        C[(size_t)row * DMODEL + col] = (f16)acc[mt][nt][r];
      }
}

// ---- scores: Eh(f16) = exp(masked QK^T/sqrt(D)); rowsum atomics; coalesced store ----
// Eh row r is stored at half-offset r*ESTRIDE (the first half of attn row r's fp32
// region) so the later in-place fp32 expansion only aliases its OWN row.
__global__ __launch_bounds__(256) void scores2(const f16* __restrict__ Q,
                                               const f16* __restrict__ Kh,
                                               const u64* __restrict__ bits,
                                               f16* __restrict__ Eh,
                                               float* __restrict__ rowsum) {
  __shared__ f16 SM[128 * 128];  // 32KB: As dbuf | Bs dbuf during GEMM; E tile after
  f16* As = SM;
  f16* Bs = SM + 8192;
  int t = threadIdx.x;
  // T1 XCD swizzle: each XCD owns 8 m-panels (1MB Q, L2-resident); within an XCD
  // m varies fastest so each K n-panel is reused 8x back-to-back.
  int orig = blockIdx.x + (blockIdx.y << 6);  // 4096 blocks, %8==0 -> bijective
  int wg = (orig & 7) * 512 + (orig >> 3);
  int m0 = (((wg >> 9) * 8 + (wg & 7))) * 128;
  int n0 = ((wg >> 3) & 63) * 128;
  int lane = t & 63, wv = t >> 6, quad = lane >> 4, l15 = lane & 15;
  int m_off = (wv & 1) * 64, n_off = (wv >> 1) * 64;
  f32x4 acc[4][4] = {};
  gemm128<DMODEL>(Q, Kh, m0, n0, As, Bs, t, acc);
  const float scale = 0.044194173824159216f;  // 1/sqrt(512)
  // gemm128's final barrier synchronized all waves; SM is free for the E tile.
#pragma unroll
  for (int mt = 0; mt < 4; ++mt)
#pragma unroll
    for (int r = 0; r < 4; ++r) {
      int lrow = m_off + mt * 16 + quad * 4 + r;
      int row = m0 + lrow;
      u64 w = bits[(size_t)row * NWORDS + ((n0 + n_off) >> 6)];  // 64 cols of this wave
      float rs = 0.f;
#pragma unroll
      for (int nt = 0; nt < 4; ++nt) {
        float s = acc[mt][nt][r] * scale;
        float e = ((w >> (nt * 16 + l15)) & 1) ? 0.f : __expf(s);
        rs += e;
        int col = n_off + nt * 16 + l15;
        // XOR-swizzle 8-half blocks with row bits -> conflict-lean, bijective per row
        int phys = (((col >> 3) ^ (lrow & 15)) << 3) | (col & 7);
        SM[lrow * 128 + phys] = (f16)e;
      }
      rs += __shfl_xor(rs, 1);
      rs += __shfl_xor(rs, 2);
      rs += __shfl_xor(rs, 4);
      rs += __shfl_xor(rs, 8);
      if (l15 == 0) atomicAdd(&rowsum[row], rs);
    }
  __syncthreads();
#pragma unroll
  for (int p = 0; p < 8; ++p) {  // coalesced f16x8 stores: 1KB per wave-instr
    int lrow = p * 16 + (t >> 4);
    int cb = t & 15;
    f16x8 v = *(const f16x8*)(SM + lrow * 128 + ((cb ^ (lrow & 15)) << 3));
    // regular store (NOT nontemporal): Eh is re-read by pv and expand -> keep in L3
    *(f16x8*)(Eh + (size_t)(m0 + lrow) * ESTRIDE + n0 + cb * 8) = v;
  }
}

// ---- pv staging: BK=32 tiles, XOR-swizzle on 16B slots (slot ^= row&3).
// Writer: linear LDS dest, pre-swizzled global column. 512 threads.
__device__ __forceinline__ void stage_pv(const f16* __restrict__ Eh,
                                         const f16* __restrict__ Vt, int r0, int kt,
                                         f16* Es, f16* Vs, int t) {
  int wv = t >> 6;
  int srcsw = (((t & 3) ^ ((t >> 2) & 3)) * 8);
  async_ld16(Eh + (size_t)(r0 + (t >> 2)) * ESTRIDE + kt + srcsw, (char*)Es + wv * 1024);
#pragma unroll
  for (int i = 0; i < 4; ++i)
    async_ld16(Vt + (size_t)(i * 128 + (t >> 2)) * NTOK + kt + srcsw,
               (char*)Vs + i * 8192 + wv * 1024);
}

// ------- cntx = (Eh @ V) * rinv; BK=32 double-buffered prefetch; K-chunked atomics -------
__global__ __launch_bounds__(512, 2) void pv_kernel(const f16* __restrict__ Eh,
                                                    const float* __restrict__ rowsum,
                                                    const f16* __restrict__ Vt,
                                                    float* __restrict__ cntx) {
  __shared__ f16 Es[2][128 * 32];  // 16 KB
  __shared__ f16 Vs[2][512 * 32];  // 64 KB
  int t = threadIdx.x;
  // XCD swizzle: 256 blocks; each XCD-chunk of 32 shares one Vt k-chunk (2MB, L2-fit)
  int orig = blockIdx.x + (blockIdx.y << 6);
  int wg = (orig & 7) * 32 + (orig >> 3);
  int r0 = (wg & 63) * 128;
  int k0 = (wg >> 6) * 2048;
  int lane = t & 63, wv = t >> 6, quad = lane >> 4, l15 = lane & 15;
  int m_off = (wv & 1) * 64, n_off = (wv >> 1) * 128;
  int sl2 = (quad ^ (l15 & 3)) * 8;  // de-swizzle for reads
  f32x4 acc[4][8] = {};
  stage_pv(Eh, Vt, r0, k0, Es[0], Vs[0], t);
  __syncthreads();
  for (int i = 0; i < 64; ++i) {
    int cur = i & 1;
    if (i < 63) stage_pv(Eh, Vt, r0, k0 + (i + 1) * 32, Es[cur ^ 1], Vs[cur ^ 1], t);
    const f16* Ec = Es[cur];
    const f16* Vc = Vs[cur];
    f16x8 af[4], bf[8];
#pragma unroll
    for (int mt = 0; mt < 4; ++mt)
      af[mt] = *(const f16x8*)(Ec + (m_off + mt * 16 + l15) * 32 + sl2);
#pragma unroll
    for (int nt = 0; nt < 8; ++nt)
      bf[nt] = *(const f16x8*)(Vc + (n_off + nt * 16 + l15) * 32 + sl2);
#pragma unroll
    for (int mt = 0; mt < 4; ++mt)
#pragma unroll
      for (int nt = 0; nt < 8; ++nt)
        acc[mt][nt] = __builtin_amdgcn_mfma_f32_16x16x32_f16(af[mt], bf[nt], acc[mt][nt], 0, 0, 0);
    __syncthreads();  // drains prefetch AFTER compute; protects cur for overwrite
  }
#pragma unroll
  for (int mt = 0; mt < 4; ++mt)
#pragma unroll
    for (int r = 0; r < 4; ++r) {
      int row = r0 + m_off + mt * 16 + quad * 4 + r;
      float ri = 1.0f / rowsum[row];
#pragma unroll
      for (int nt = 0; nt < 8; ++nt) {
        int col = n_off + nt * 16 + l15;
        atomicAdd(&cntx[(size_t)row * DMODEL + col], acc[mt][nt][r] * ri);
      }
    }
}

// ---- in-place f16 E -> fp32 attn * rinv, pure-register (no LDS, no barriers).
// One wave per row. All 16 loads precede all stores in program order; src/dst
// may alias so the compiler cannot hoist a store above a load; the HW waits
// (wave-level vmcnt) cover all 64 lanes' loads before the first dependent store.
// fp32 write of col c only clobbers f16 cols >= c, all within this wave's row.
// Runs LAST, so nontemporal (no-allocate) loads/stores are safe here.
__global__ __launch_bounds__(256) void expand_attn(float* __restrict__ attn,
                                                   const float* __restrict__ rowsum) {
  int t = threadIdx.x;
  int wv = t >> 6, lane = t & 63;
  int row = blockIdx.x * 4 + wv;
  float ri = 1.0f / rowsum[row];
  const f16* src = (const f16*)(attn + (size_t)row * NTOK);
  float* dst = attn + (size_t)row * NTOK;
  f16x8 v0, v1, v2, v3, v4, v5, v6, v7, v8, v9, va, vb, vc, vd, ve, vf;
#define LD(i, reg) reg = __builtin_nontemporal_load((const f16x8*)(src + (i) * 512 + lane * 8))
  LD(0, v0); LD(1, v1); LD(2, v2); LD(3, v3); LD(4, v4); LD(5, v5); LD(6, v6); LD(7, v7);
  LD(8, v8); LD(9, v9); LD(10, va); LD(11, vb); LD(12, vc); LD(13, vd); LD(14, ve); LD(15, vf);
#undef LD
  asm volatile("" ::: "memory");  // compiler barrier: pin all loads before any store
#define ST(i, reg)                                                            \
  {                                                                           \
    f32x4 lo, hi;                                                             \
    lo.x = (float)reg[0] * ri; lo.y = (float)reg[1] * ri;                     \
    lo.z = (float)reg[2] * ri; lo.w = (float)reg[3] * ri;                     \
    hi.x = (float)reg[4] * ri; hi.y = (float)reg[5] * ri;                     \
    hi.z = (float)reg[6] * ri; hi.w = (float)reg[7] * ri;                     \
    __builtin_nontemporal_store(lo, (f32x4*)(dst + (i) * 512 + lane * 8));    \
    __builtin_nontemporal_store(hi, (f32x4*)(dst + (i) * 512 + lane * 8 + 4)); \
  }
  ST(0, v0); ST(1, v1); ST(2, v2); ST(3, v3); ST(4, v4); ST(5, v5); ST(6, v6); ST(7, v7);
  ST(8, v8); ST(9, v9); ST(10, va); ST(11, vb); ST(12, vc); ST(13, vd); ST(14, ve); ST(15, vf);
#undef ST
}

extern "C" void kernel_launch(void* const* d_in, const int* in_sizes, int n_in,
                              void* d_out, int out_size, void* d_ws, size_t ws_size,
                              hipStream_t stream) {
  const float* x  = (const float*)d_in[0];
  const int* mask = (const int*)d_in[1];
  const float* Wq = (const float*)d_in[2];
  const float* Wk = (const float*)d_in[3];
  const float* Wv = (const float*)d_in[4];
  float* cntx = (float*)d_out;
  float* attn = (float*)d_out + (size_t)NTOK * DMODEL;

  // workspace (f16): xh 8MB | Wh 1.5MB | Q,K,V 24MB | Vt 8MB | rowsum 32KB  (~42MB)
  f16* xh = (f16*)d_ws;
  f16* Wh = xh + (size_t)NTOK * DMODEL;
  f16* QKV = Wh + (size_t)3 * DMODEL * DMODEL;
  f16* Qh = QKV;
  f16* Kh = QKV + (size_t)NTOK * DMODEL;
  f16* Vh = QKV + (size_t)2 * NTOK * DMODEL;
  f16* Vt = QKV + (size_t)3 * NTOK * DMODEL;
  float* rowsum = (float*)(Vt + (size_t)NTOK * DMODEL);

  // bitmask (8MB) lives in the cntx output region: dead until after scores2.
  u64* bits = (u64*)cntx;
  // f16 E lives interleaved in the attn output region (first half of each fp32 row).
  f16* Eh = (f16*)attn;

  hipMemsetAsync(rowsum, 0, NTOK * sizeof(float), stream);

  pack_f16<<<dim3(NTOK * DMODEL / 1024), 256, 0, stream>>>(x, xh, NTOK * DMODEL);
  pack_f16<<<dim3(DMODEL * DMODEL / 1024), 256, 0, stream>>>(Wq, Wh, DMODEL * DMODEL);
  pack_f16<<<dim3(DMODEL * DMODEL / 1024), 256, 0, stream>>>(Wk, Wh + DMODEL * DMODEL, DMODEL * DMODEL);
  pack_f16<<<dim3(DMODEL * DMODEL / 1024), 256, 0, stream>>>(Wv, Wh + 2 * DMODEL * DMODEL, DMODEL * DMODEL);
  pack_mask<<<dim3(NTOK * NWORDS / 8 / 4), 256, 0, stream>>>(mask, bits);

  qkv_gemm<<<dim3(DMODEL / 128, NTOK / 128, 3), 256, 0, stream>>>(xh, Wh, QKV);
  transpose_f16<<<dim3(NTOK / 64, DMODEL / 64), 256, 0, stream>>>(Vh, Vt);
  scores2<<<dim3(NTOK / 128, NTOK / 128), 256, 0, stream>>>(Qh, Kh, bits, Eh, rowsum);

  // bits now dead; zero cntx for pv atomics
  hipMemsetAsync(cntx, 0, (size_t)NTOK * DMODEL * sizeof(float), stream);
  pv_kernel<<<dim3(NTOK / 128, 4), 512, 0, stream>>>(Eh, rowsum, Vt, cntx);
  expand_attn<<<dim3(NTOK / 4), 256, 0, stream>>>(attn, rowsum);
}

// Round 7
// 808.392 us; speedup vs baseline: 1.1126x; 1.0778x over previous
//
#include <hip/hip_runtime.h>

#define NTOK 8192
#define DMODEL 512
#define NWORDS 128  // NTOK/64 mask words per row

typedef _Float16 f16;
typedef _Float16 f16x4 __attribute__((ext_vector_type(4)));
typedef _Float16 f16x8 __attribute__((ext_vector_type(8)));
typedef float f32x4 __attribute__((ext_vector_type(4)));
typedef unsigned long long u64;

// async global->LDS, 16B per lane; lds dest = wave-uniform base + lane*16
__device__ __forceinline__ void async_ld16(const void* g, void* l) {
  __builtin_amdgcn_global_load_lds((const __attribute__((address_space(1))) void*)g,
                                   (__attribute__((address_space(3))) void*)l, 16, 0, 0);
}

// ---------------- pack fp32 -> f16 (elementwise, float4 vectorized) ----------------
__global__ void pack_f16(const float* __restrict__ s, f16* __restrict__ d, int n) {
  int i = (blockIdx.x * 256 + threadIdx.x) * 4;
  if (i >= n) return;
  float4 v = *(const float4*)(s + i);
  f16x4 h; h.x = (f16)v.x; h.y = (f16)v.y; h.z = (f16)v.z; h.w = (f16)v.w;
  *(f16x4*)(d + i) = h;
}

// ------------- mask int32 -> bitmask: 256MB -> 8MB, pure streaming -------------
__global__ __launch_bounds__(256) void pack_mask(const int* __restrict__ mask,
                                                 u64* __restrict__ bits) {
  int wave = (blockIdx.x * 256 + threadIdx.x) >> 6;
  int lane = threadIdx.x & 63;
  size_t W0 = (size_t)wave * 8;
#pragma unroll
  for (int i = 0; i < 8; ++i) {
    int m = __builtin_nontemporal_load(mask + (W0 + i) * 64 + lane);  // read-once
    u64 b = __ballot(m != 0);  // bit l = col W*64+l
    if (lane == 0) bits[W0 + i] = b;
  }
}

// ---------------- transpose V [NTOK][D] -> Vt [D][NTOK] ----------------
__global__ __launch_bounds__(256) void transpose_f16(const f16* __restrict__ src,
                                                     f16* __restrict__ dst) {
  __shared__ f16 T[64][72];  // +8 pad breaks bank alignment
  int t = threadIdx.x;
  int tok0 = blockIdx.x * 64, d0 = blockIdx.y * 64;
#pragma unroll
  for (int i = 0; i < 2; ++i) {
    int row = (t >> 3) + i * 32;
    int col = (t & 7) * 8;
    f16x8 v = *(const f16x8*)(src + (size_t)(tok0 + row) * DMODEL + d0 + col);
    *(f16x8*)(&T[row][col]) = v;
  }
  __syncthreads();
#pragma unroll
  for (int i = 0; i < 2; ++i) {
    int od = (t >> 3) + i * 32;
    int ot = (t & 7) * 8;
    f16x8 v;
#pragma unroll
    for (int j = 0; j < 8; ++j) v[j] = T[ot + j][od];
    *(f16x8*)(dst + (size_t)(d0 + od) * NTOK + tok0 + ot) = v;
  }
}

// ---- stage 128x32 f16 tile, XOR-swizzled 16B slots (rule #21: linear LDS dest
// via global_load_lds + pre-swizzled GLOBAL slot; reader applies the same XOR).
// LDS[row][slot] = G[row][slot ^ (row&3)] (slots of 8 halfs). 2 issues/thread.
__device__ __forceinline__ void stage128x32(const f16* G, int r0, int k0, int rs,
                                            f16* lds, int t) {
  int wv = t >> 6;
  int srcsw = (((t & 3) ^ ((t >> 2) & 3)) * 8);
  const f16* g = G + (size_t)(r0 + (t >> 2)) * rs + k0 + srcsw;
  async_ld16(g, (char*)lds + wv * 1024);                         // rows 0..63
  async_ld16(g + (size_t)64 * rs, (char*)lds + 4096 + wv * 1024);  // rows 64..127
}

// shared 128x128 C = A * B^T K-loop, BK=32, double-buffered at 32KB total
// (m132 lesson: never pay occupancy for dbuf).
template <int RS>
__device__ __forceinline__ void gemm128(const f16* A, const f16* B, int m0, int n0,
                                        f16* As, f16* Bs, int t, f32x4 (&acc)[4][4]) {
  int lane = t & 63, quad = lane >> 4, l15 = lane & 15, wv = t >> 6;
  int m_off = (wv & 1) * 64, n_off = (wv >> 1) * 64;
  int sl = (quad ^ (l15 & 3)) * 8;  // de-swizzle: source slot quad at LDS slot quad^(row&3)
  stage128x32(A, m0, 0, RS, As, t);
  stage128x32(B, n0, 0, RS, Bs, t);
  __syncthreads();
  for (int kt = 0; kt < RS; kt += 32) {
    int cur = (kt >> 5) & 1;
    if (kt + 32 < RS) {  // prefetch next K-tile into the other buffer
      stage128x32(A, m0, kt + 32, RS, As + (cur ^ 1) * 4096, t);
      stage128x32(B, n0, kt + 32, RS, Bs + (cur ^ 1) * 4096, t);
    }
    const f16* Ac = As + cur * 4096;
    const f16* Bc = Bs + cur * 4096;
    f16x8 af[4], bf[4];
#pragma unroll
    for (int mt = 0; mt < 4; ++mt)
      af[mt] = *(const f16x8*)(Ac + (m_off + mt * 16 + l15) * 32 + sl);
#pragma unroll
    for (int nt = 0; nt < 4; ++nt)
      bf[nt] = *(const f16x8*)(Bc + (n_off + nt * 16 + l15) * 32 + sl);
#pragma unroll
    for (int mt = 0; mt < 4; ++mt)
#pragma unroll
      for (int nt = 0; nt < 4; ++nt)
        acc[mt][nt] = __builtin_amdgcn_mfma_f32_16x16x32_f16(af[mt], bf[nt], acc[mt][nt], 0, 0, 0);
    __syncthreads();  // drains prefetch vmcnt AFTER compute; protects cur for overwrite
  }
}

// ---------------- QKV: C[i,j] = sum_k X[i,k] * W[j,k] ----------------
__global__ __launch_bounds__(256) void qkv_gemm(const f16* __restrict__ X,
                                                const f16* __restrict__ Wall,
                                                f16* __restrict__ Out) {
  __shared__ f16 As[2 * 128 * 32];  // 16 KB
  __shared__ f16 Bs[2 * 128 * 32];  // 16 KB
  int t = threadIdx.x;
  int z = blockIdx.z;
  const f16* B = Wall + (size_t)z * DMODEL * DMODEL;
  f16* C = Out + (size_t)z * NTOK * DMODEL;
  int m0 = blockIdx.y * 128, n0 = blockIdx.x * 128;
  int lane = t & 63, wv = t >> 6, quad = lane >> 4, l15 = lane & 15;
  int m_off = (wv & 1) * 64, n_off = (wv >> 1) * 64;
  f32x4 acc[4][4] = {};
  gemm128<DMODEL>(X, B, m0, n0, As, Bs, t, acc);
#pragma unroll
  for (int mt = 0; mt < 4; ++mt)
#pragma unroll
    for (int nt = 0; nt < 4; ++nt)
#pragma unroll
      for (int r = 0; r < 4; ++r) {
        int row = m0 + m_off + mt * 16 + quad * 4 + r;
        int col = n0 + n_off + nt * 16 + l15;
        C[(size_t)row * DMODEL + col] = (f16)acc[mt][nt][r];
      }
}

// ---- scores: Eh(f16, dense [NTOK][NTOK] in ws) = exp(masked QK^T/sqrt(D));
// rowsum atomics; coalesced 256B/row stores.
__global__ __launch_bounds__(256) void scores2(const f16* __restrict__ Q,
                                               const f16* __restrict__ Kh,
                                               const u64* __restrict__ bits,
                                               f16* __restrict__ Eh,
                                               float* __restrict__ rowsum) {
  __shared__ f16 SM[128 * 128];  // 32KB: As dbuf | Bs dbuf during GEMM; E tile after
  f16* As = SM;
  f16* Bs = SM + 8192;
  int t = threadIdx.x;
  // T1 XCD swizzle: each XCD owns 8 m-panels (1MB Q, L2-resident); within an XCD
  // m varies fastest so each K n-panel is reused 8x back-to-back.
  int orig = blockIdx.x + (blockIdx.y << 6);  // 4096 blocks, %8==0 -> bijective
  int wg = (orig & 7) * 512 + (orig >> 3);
  int m0 = (((wg >> 9) * 8 + (wg & 7))) * 128;
  int n0 = ((wg >> 3) & 63) * 128;
  int lane = t & 63, wv = t >> 6, quad = lane >> 4, l15 = lane & 15;
  int m_off = (wv & 1) * 64, n_off = (wv >> 1) * 64;
  f32x4 acc[4][4] = {};
  gemm128<DMODEL>(Q, Kh, m0, n0, As, Bs, t, acc);
  const float scale = 0.044194173824159216f;  // 1/sqrt(512)
  // gemm128's final barrier synchronized all waves; SM is free for the E tile.
#pragma unroll
  for (int mt = 0; mt < 4; ++mt)
#pragma unroll
    for (int r = 0; r < 4; ++r) {
      int lrow = m_off + mt * 16 + quad * 4 + r;
      int row = m0 + lrow;
      u64 w = bits[(size_t)row * NWORDS + ((n0 + n_off) >> 6)];  // 64 cols of this wave
      float rs = 0.f;
#pragma unroll
      for (int nt = 0; nt < 4; ++nt) {
        float s = acc[mt][nt][r] * scale;
        float e = ((w >> (nt * 16 + l15)) & 1) ? 0.f : __expf(s);
        rs += e;
        int col = n_off + nt * 16 + l15;
        // XOR-swizzle 8-half blocks with row bits -> conflict-lean, bijective per row
        int phys = (((col >> 3) ^ (lrow & 15)) << 3) | (col & 7);
        SM[lrow * 128 + phys] = (f16)e;
      }
      rs += __shfl_xor(rs, 1);
      rs += __shfl_xor(rs, 2);
      rs += __shfl_xor(rs, 4);
      rs += __shfl_xor(rs, 8);
      if (l15 == 0) atomicAdd(&rowsum[row], rs);
    }
  __syncthreads();
#pragma unroll
  for (int p = 0; p < 8; ++p) {  // coalesced f16x8 stores: 1KB per wave-instr
    int lrow = p * 16 + (t >> 4);
    int cb = t & 15;
    f16x8 v = *(const f16x8*)(SM + lrow * 128 + ((cb ^ (lrow & 15)) << 3));
    *(f16x8*)(Eh + (size_t)(m0 + lrow) * NTOK + n0 + cb * 8) = v;  // keep in L3
  }
}

// ---- pv staging: BK=32 tiles, XOR-swizzle on 16B slots (slot ^= row&3).
// Writer: linear LDS dest, pre-swizzled global column. 512 threads.
__device__ __forceinline__ void stage_pv(const f16* __restrict__ Eh,
                                         const f16* __restrict__ Vt, int r0, int kt,
                                         f16* Es, f16* Vs, int t) {
  int wv = t >> 6;
  int srcsw = (((t & 3) ^ ((t >> 2) & 3)) * 8);
  async_ld16(Eh + (size_t)(r0 + (t >> 2)) * NTOK + kt + srcsw, (char*)Es + wv * 1024);
#pragma unroll
  for (int i = 0; i < 4; ++i)
    async_ld16(Vt + (size_t)(i * 128 + (t >> 2)) * NTOK + kt + srcsw,
               (char*)Vs + i * 8192 + wv * 1024);
}

// ------- pv_fused: cntx = (Eh @ V) * rinv  AND  attn = Eh * rinv (fp32).
// Each staged Es tile is re-read from LDS (linear, conflict-free), scaled,
// and NT-stored to attn -- the 256MB attn write rides on reads already paid.
__global__ __launch_bounds__(512, 2) void pv_fused(const f16* __restrict__ Eh,
                                                   const float* __restrict__ rowsum,
                                                   const f16* __restrict__ Vt,
                                                   float* __restrict__ cntx,
                                                   float* __restrict__ attn) {
  __shared__ f16 Es[2][128 * 32];  // 16 KB
  __shared__ f16 Vs[2][512 * 32];  // 64 KB
  int t = threadIdx.x;
  // 256 blocks = 64 r0 x 4 k-chunks. chunk = orig&3 (XCD pairs share a 2MB Vt
  // chunk, L2-resident); r0 staggered by 16 per chunk so the 4 chunks' atomics
  // to the same cntx rows never collide in time.
  int orig = blockIdx.x;
  int chunk = orig & 3;
  int r0 = (((orig >> 2) + chunk * 16) & 63) * 128;
  int k0 = chunk * 2048;
  int lane = t & 63, wv = t >> 6, quad = lane >> 4, l15 = lane & 15;
  int m_off = (wv & 1) * 64, n_off = (wv >> 1) * 128;
  int sl2 = (quad ^ (l15 & 3)) * 8;  // de-swizzle for MFMA fragment reads
  // attn-write lane mapping: thread t holds Es bytes [t*16, t*16+16) = row t>>2,
  // phys slot t&3, source slot (t&3)^(row&3).
  int arow = t >> 2;
  int aslot = (t & 3) ^ (arow & 3);
  float rinv = 1.0f / rowsum[r0 + arow];
  f32x4 acc[4][8] = {};
  stage_pv(Eh, Vt, r0, k0, Es[0], Vs[0], t);
  __syncthreads();
  for (int i = 0; i < 64; ++i) {
    int cur = i & 1;
    if (i < 63) stage_pv(Eh, Vt, r0, k0 + (i + 1) * 32, Es[cur ^ 1], Vs[cur ^ 1], t);
    const f16* Ec = Es[cur];
    const f16* Vc = Vs[cur];
    // normalized fp32 attn write for this tile (LDS read linear: zero conflicts)
    {
      f16x8 ev = *(const f16x8*)(Ec + t * 8);
      f32x4 lo, hi;
      lo.x = (float)ev[0] * rinv; lo.y = (float)ev[1] * rinv;
      lo.z = (float)ev[2] * rinv; lo.w = (float)ev[3] * rinv;
      hi.x = (float)ev[4] * rinv; hi.y = (float)ev[5] * rinv;
      hi.z = (float)ev[6] * rinv; hi.w = (float)ev[7] * rinv;
      float* ap = attn + (size_t)(r0 + arow) * NTOK + k0 + i * 32 + aslot * 8;
      __builtin_nontemporal_store(lo, (f32x4*)ap);
      __builtin_nontemporal_store(hi, (f32x4*)(ap + 4));
    }
    f16x8 af[4], bf[8];
#pragma unroll
    for (int mt = 0; mt < 4; ++mt)
      af[mt] = *(const f16x8*)(Ec + (m_off + mt * 16 + l15) * 32 + sl2);
#pragma unroll
    for (int nt = 0; nt < 8; ++nt)
      bf[nt] = *(const f16x8*)(Vc + (n_off + nt * 16 + l15) * 32 + sl2);
#pragma unroll
    for (int mt = 0; mt < 4; ++mt)
#pragma unroll
      for (int nt = 0; nt < 8; ++nt)
        acc[mt][nt] = __builtin_amdgcn_mfma_f32_16x16x32_f16(af[mt], bf[nt], acc[mt][nt], 0, 0, 0);
    __syncthreads();  // drains prefetch AFTER compute; protects cur for overwrite
  }
#pragma unroll
  for (int mt = 0; mt < 4; ++mt)
#pragma unroll
    for (int r = 0; r < 4; ++r) {
      int row = r0 + m_off + mt * 16 + quad * 4 + r;
      float ri = 1.0f / rowsum[row];
#pragma unroll
      for (int nt = 0; nt < 8; ++nt) {
        int col = n_off + nt * 16 + l15;
        atomicAdd(&cntx[(size_t)row * DMODEL + col], acc[mt][nt][r] * ri);
      }
    }
}

extern "C" void kernel_launch(void* const* d_in, const int* in_sizes, int n_in,
                              void* d_out, int out_size, void* d_ws, size_t ws_size,
                              hipStream_t stream) {
  const float* x  = (const float*)d_in[0];
  const int* mask = (const int*)d_in[1];
  const float* Wq = (const float*)d_in[2];
  const float* Wk = (const float*)d_in[3];
  const float* Wv = (const float*)d_in[4];
  float* cntx = (float*)d_out;
  float* attn = (float*)d_out + (size_t)NTOK * DMODEL;

  // workspace: xh 8MB | Wh 1.5MB | Q,K,V 24MB | Vt 8MB | rowsum 32KB | Eh 128MB
  // | bits 8MB  (~178 MB; poison fills show ws >= ~1GB)
  f16* xh = (f16*)d_ws;
  f16* Wh = xh + (size_t)NTOK * DMODEL;
  f16* QKV = Wh + (size_t)3 * DMODEL * DMODEL;
  f16* Qh = QKV;
  f16* Kh = QKV + (size_t)NTOK * DMODEL;
  f16* Vh = QKV + (size_t)2 * NTOK * DMODEL;
  f16* Vt = QKV + (size_t)3 * NTOK * DMODEL;
  float* rowsum = (float*)(Vt + (size_t)NTOK * DMODEL);
  f16* Eh = (f16*)(rowsum + NTOK);
  u64* bits = (u64*)(Eh + (size_t)NTOK * NTOK);

  hipMemsetAsync(rowsum, 0, NTOK * sizeof(float), stream);
  hipMemsetAsync(cntx, 0, (size_t)NTOK * DMODEL * sizeof(float), stream);

  pack_f16<<<dim3(NTOK * DMODEL / 1024), 256, 0, stream>>>(x, xh, NTOK * DMODEL);
  pack_f16<<<dim3(DMODEL * DMODEL / 1024), 256, 0, stream>>>(Wq, Wh, DMODEL * DMODEL);
  pack_f16<<<dim3(DMODEL * DMODEL / 1024), 256, 0, stream>>>(Wk, Wh + DMODEL * DMODEL, DMODEL * DMODEL);
  pack_f16<<<dim3(DMODEL * DMODEL / 1024), 256, 0, stream>>>(Wv, Wh + 2 * DMODEL * DMODEL, DMODEL * DMODEL);
  pack_mask<<<dim3(NTOK * NWORDS / 8 / 4), 256, 0, stream>>>(mask, bits);

  qkv_gemm<<<dim3(DMODEL / 128, NTOK / 128, 3), 256, 0, stream>>>(xh, Wh, QKV);
  transpose_f16<<<dim3(NTOK / 64, DMODEL / 64), 256, 0, stream>>>(Vh, Vt);
  scores2<<<dim3(NTOK / 128, NTOK / 128), 256, 0, stream>>>(Qh, Kh, bits, Eh, rowsum);
  pv_fused<<<dim3(256), 512, 0, stream>>>(Eh, rowsum, Vt, cntx, attn);
}